// Round 13
// baseline (127.060 us; speedup 1.0000x reference)
//
#include <hip/hip_runtime.h>

// Problem constants
#define B_    1024
#define C_    128
#define ELL   16
#define EQ    3
#define E_    10
#define P3    23
#define P2    5
#define NSEG  176            // padded segment row: 16 f4-aligned v-segments
#define RSTR  180            // row stride (180%32=20 -> 8 bank-starts x2 = 2-way, free)
#define SRS   (48 * RSTR)    // 8640 floats per (e,c) S-slice
#define KD    28             // folded weight depth: 23 (wmax) + 5 (w2)

// packed fp32 pair: clang emits v_pk_fma_f32 / v_pk_mul_f32 for <2 x float>
typedef float v2f __attribute__((ext_vector_type(2)));

// ws layout (bytes)
#define WS_CNT   0
#define WS_LIST  64
#define WS_S     65536              // Sg: 10*128*8640*4 = 44.24 MB
#define WS_SKL   50331648           // SKLg: 48*176*28*4 = 945 KB (ws >= 66 MB)

// segment offsets: v-th segment holds [lin_v, Q_vv, Q_v,v+1, .., Q_v,15, pad0s]
// lengths (real) 17-v, padded to x4: {20,16,16,16,16,12,12,12,12,8,8,8,8,4,4,4}
#define SEG_OFF_INIT {0,20,36,52,68,84,96,108,120,132,140,148,156,164,168,172}

// DPP row_ror add: lane i += lane (i+N) mod 16 within its 16-lane DPP row.
// Chained over N=1,2,4,8: width-16 sum-to-all; bit-identical tree to the
// __shfl_xor butterfly for the storing lanes. VERIFIED r18b/r19/r20/r23.
template <int CTRL>
__device__ __forceinline__ float dpp_ror_add(float v) {
    int s = __float_as_int(v);
    int r = __builtin_amdgcn_update_dpp(s, s, CTRL, 0xF, 0xF, false);
    return v + __int_as_float(r);
}
__device__ __forceinline__ float row16_sum(float v) {
    v = dpp_ror_add<0x121>(v);   // row_ror:1
    v = dpp_ror_add<0x122>(v);   // row_ror:2
    v = dpp_ror_add<0x124>(v);   // row_ror:4
    v = dpp_ror_add<0x128>(v);   // row_ror:8
    return v;
}

// ---------------------------------------------------------------------------
// Bucketing: bucket batch indices by element, pad each bucket to x64 by
// replicating the last real index (k_main needs no load guards). Exact r19.
__device__ void do_lists(const float* __restrict__ y, int* __restrict__ cnt_g,
                         int* __restrict__ list_g, int t) {
    __shared__ int lcnt[E_];
    if (t < E_) lcnt[t] = 0;
    __syncthreads();
    for (int r = 0; r < 4; ++r) {
        int b = t + 256 * r;
        int e = 0;
        #pragma unroll
        for (int j = 1; j < E_; ++j)
            if (y[b * E_ + j] > 0.5f) e = j;
        int slot = atomicAdd(&lcnt[e], 1);
        list_g[e * B_ + slot] = b;
    }
    __syncthreads();
    if (t < E_) {
        int c0 = lcnt[t];
        cnt_g[t] = c0;
        int last = (c0 > 0) ? list_g[t * B_ + c0 - 1] : 0;
        int cp = (c0 + 63) & ~63;
        if (cp > B_) cp = B_;
        for (int s2 = c0; s2 < cp; ++s2) list_g[t * B_ + s2] = last;
    }
}

// ---------------------------------------------------------------------------
// k_skl (NEW r24): one-time symmetrized-coefficient build.
// SKLg[j][slot][d] depends ONLY on U3/U2 (not e, not c) -- the old k_s
// phase-1b recomputed it in all 1920 blocks (40x redundant, 176 threads x
// ~46 SCATTERED U3 loads each, on the pre-barrier critical path).
// 48 blocks, one-time, 945 KB -> L2-resident for k_s.
__global__ __launch_bounds__(192, 4) void k_skl(const float* __restrict__ U3,
                                                const float* __restrict__ U2,
                                                float* __restrict__ SKLg) {
    const int j = blockIdx.x;
    const int t = threadIdx.x;
    if (t >= NSEG) return;

    const int SO[16] = SEG_OFF_INIT;
    int v = 0;
    #pragma unroll
    for (int s = 1; s < 16; ++s) v += (t >= SO[s]) ? 1 : 0;
    const int l    = t - SO[v];
    const int real = 17 - v;

    float row[KD];
    #pragma unroll
    for (int d = 0; d < KD; ++d) row[d] = 0.f;

    if (l == 0) {
        #pragma unroll
        for (int q = 0; q < P2; ++q)
            row[23 + q] = U2[(size_t)j * (ELL * P2) + v * P2 + q];
    } else if (l < real) {
        int i = v + l - 1;
        const float* pa = U3 + (size_t)j * (ELL * ELL * P3) + (v * ELL + i) * P3;
        const float* pb = U3 + (size_t)j * (ELL * ELL * P3) + (i * ELL + v) * P3;
        if (i != v) {
            #pragma unroll
            for (int k = 0; k < P3; ++k) row[k] = pa[k] + pb[k];
        } else {
            #pragma unroll
            for (int k = 0; k < P3; ++k) row[k] = pa[k];
        }
    }   // else: pad slot -> stays zero

    float* dst = SKLg + ((size_t)j * NSEG + t) * KD;   // 112B-aligned
    #pragma unroll
    for (int d4 = 0; d4 < KD / 4; ++d4)
        *(float4*)(dst + 4 * d4) = make_float4(row[4 * d4], row[4 * d4 + 1],
                                               row[4 * d4 + 2], row[4 * d4 + 3]);
}

// ---------------------------------------------------------------------------
// k_s r24: phase-2 fold unchanged (r17-verified); phase-1b replaced by a
// coalesced LDS copy of the precomputed SKLg[j] (1232 f4, ~5 f4/thread,
// L2-hit) instead of the 46-scattered-load symmetrize.
__global__ __launch_bounds__(256, 2) void k_s(const float* __restrict__ SKLg,
                                              const float* __restrict__ wmax,
                                              const float* __restrict__ w2,
                                              const float* __restrict__ y,
                                              float* __restrict__ Sg,
                                              int* __restrict__ cnt_g,
                                              int* __restrict__ list_g) {
    const int t = threadIdx.x;
    if (blockIdx.x == 48) {
        if (blockIdx.y == 0 && blockIdx.z == 0) do_lists(y, cnt_g, list_g, t);
        return;
    }
    __shared__ __align__(16) float wsm[KD * 32];          //  3,584 B
    __shared__ __align__(16) float SKL[NSEG * KD];        // 19,712 B

    const int j  = blockIdx.x;
    const int e  = blockIdx.y;
    const int cq = blockIdx.z;

    // ---- phase 1a: folded weight table (23 wmax + 5 w2) for this (e, cq)
    for (int idx = t; idx < KD * 32; idx += 256) {
        int k = idx >> 5, cc = idx & 31, c = cq * 32 + cc;
        wsm[idx] = (k < 23) ? wmax[(e * P3 + k) * C_ + c]
                            : w2[(e * P2 + (k - 23)) * C_ + c];
    }

    // ---- phase 1b: stage SKLg[j] -> LDS (4928 floats = 1232 f4, coalesced)
    {
        const float4* src4 = (const float4*)(SKLg + (size_t)j * (NSEG * KD));
        float4* dst4 = (float4*)SKL;
        for (int f = t; f < 1232; f += 256) dst4[f] = src4[f];
    }
    __syncthreads();

    if (t >= NSEG) return;

    // ---- phase 2: 4 slots x 8 c per thread, packed fp32 (r17-verified)
    const int sg = t % 44;          // slot group: slots sg, sg+44, sg+88, sg+132
    const int cg = t / 44;          // 0..3 -> c8 = cg*8
    const int c8 = cg * 8;

    v2f acc[4][4];                  // [s][c-pair]
    #pragma unroll
    for (int s = 0; s < 4; ++s)
        #pragma unroll
        for (int cp2 = 0; cp2 < 4; ++cp2) acc[s][cp2] = (v2f){0.f, 0.f};

    #pragma unroll
    for (int k4 = 0; k4 < KD / 4; ++k4) {
        float4 sk4[4];
        #pragma unroll
        for (int s = 0; s < 4; ++s)
            sk4[s] = *(const float4*)&SKL[(sg + 44 * s) * KD + 4 * k4];
        #pragma unroll
        for (int kk = 0; kk < 4; ++kk) {
            const int k = 4 * k4 + kk;
            float4 w0 = *(const float4*)&wsm[k * 32 + c8];
            float4 w1 = *(const float4*)&wsm[k * 32 + c8 + 4];
            v2f wp0 = {w0.x, w0.y}, wp1 = {w0.z, w0.w};
            v2f wp2 = {w1.x, w1.y}, wp3 = {w1.z, w1.w};
            #pragma unroll
            for (int s = 0; s < 4; ++s) {
                const float skv = (kk == 0) ? sk4[s].x : (kk == 1) ? sk4[s].y
                                : (kk == 2) ? sk4[s].z : sk4[s].w;
                acc[s][0] += skv * wp0;
                acc[s][1] += skv * wp1;
                acc[s][2] += skv * wp2;
                acc[s][3] += skv * wp3;
            }
        }
    }

    // ---- stores: lane-consecutive in slot -> coalesced 44-lane runs
    #pragma unroll
    for (int s = 0; s < 4; ++s) {
        const int slot = sg + 44 * s;
        #pragma unroll
        for (int cc = 0; cc < 8; ++cc) {
            const int c = cq * 32 + c8 + cc;
            Sg[(size_t)(e * C_ + c) * SRS + j * RSTR + slot] = acc[s][cc >> 1][cc & 1];
        }
    }
}

// ---------------------------------------------------------------------------
// k_main r24 = EXACT r23 (best: 42.1us, VGPR 64, no spill). r23 post-mortem:
// (256,4) left occupancy at 33% (192-VGPR theory falsified) but VALUBusy
// rose to 80-85% -> k_main is within ~15% of its VALU-issue floor at the
// real sustained clock. Marginal k_main levers are exhausted (2x2 matrix
// r14/r17/r19/r20 + TLP r15/r21 + transpose r22 all flat or worse).
// CRITICAL (unchanged): __syncthreads() pin + unroll(disable) -- LICM
// hoisting LDS reads caused the r5/r6 VGPR blowup/spill.
__global__ __launch_bounds__(256, 4) void k_main(
    const float* __restrict__ x, const float* __restrict__ Sg,
    const float* __restrict__ U1, const float* __restrict__ w1,
    const int* __restrict__ cnt_g, const int* __restrict__ list_g,
    float* __restrict__ out) {

    __shared__ __align__(16) float V3L[16 * RSTR];   // 11,520 B

    const int t  = threadIdx.x;
    const int bx = blockIdx.x;
    const int w  = bx % 3, c = bx / 3;
    const int e  = blockIdx.y;
    const int xx = t & 15, bs = t >> 4;
    const int cnt  = cnt_g[e];
    const int cntp = (cnt + 63) & ~63;

    // ---- fill V3L: this w's 16 rows = 2880 floats = 720 f4, straight copy
    {
        const float4* src = (const float4*)(Sg + (size_t)(e * C_ + c) * SRS
                                            + (size_t)w * 16 * RSTR);
        float4* dst = (float4*)V3L;
        #pragma unroll
        for (int r = 0; r < 2; ++r) dst[t + 256 * r] = src[t + 256 * r];
        if (t < 208) dst[512 + t] = src[512 + t];
    }
    const float v1x = U1[w * 16 + xx] * w1[e * C_ + c];
    __syncthreads();

    const float* v3p = &V3L[xx * RSTR];
    const int SO[16] = SEG_OFF_INIT;

    // ---- chunk loop: 64 rows per chunk, 4 per thread ----
    #pragma clang loop unroll(disable)
    for (int base = 0; base < cntp; base += 64) {
        __syncthreads();   // anti-LICM liveness pin (see header note)

        const int slot = base + bs * 4;
        int bidx[4];
        #pragma unroll
        for (int r = 0; r < 4; ++r) bidx[r] = list_g[e * B_ + slot + r];

        float xm[4][16];
        float xo[4];
        #pragma unroll
        for (int r = 0; r < 4; ++r) {
            const float* xb = x + ((size_t)bidx[r] * C_ + c) * ELL;
            #pragma unroll
            for (int i4 = 0; i4 < 4; ++i4) {
                float4 a = ((const float4*)xb)[i4];
                xm[r][4 * i4 + 0] = a.x; xm[r][4 * i4 + 1] = a.y;
                xm[r][4 * i4 + 2] = a.z; xm[r][4 * i4 + 3] = a.w;
            }
            xo[r] = xb[xx];   // own-x element (L1 hit; no dynamic reg index)
        }

        float t2[4] = {0.f, 0.f, 0.f, 0.f};
        #pragma unroll
        for (int v = 0; v < 16; ++v) {
            const int off = SO[v];
            const int nf4 = (v == 0) ? 5 : (v < 5) ? 4 : (v < 9) ? 3 : (v < 13) ? 2 : 1;
            float inner[4];
            {   // first f4: [lin, Q_vv, Q_v,v+1, Q_v,v+2]
                float4 u = *(const float4*)(v3p + off);
                #pragma unroll
                for (int r = 0; r < 4; ++r) {
                    float s = u.x + u.y * xm[r][v];
                    if (v + 1 <= 15) s += u.z * xm[r][v + 1];
                    if (v + 2 <= 15) s += u.w * xm[r][v + 2];
                    inner[r] = s;
                }
            }
            #pragma unroll
            for (int q = 1; q < nf4; ++q) {
                float4 u = *(const float4*)(v3p + off + 4 * q);
                const int i0 = v + 4 * q - 1;
                #pragma unroll
                for (int r = 0; r < 4; ++r) {
                    inner[r] += u.x * xm[r][i0];
                    if (i0 + 1 <= 15) inner[r] += u.y * xm[r][i0 + 1];
                    if (i0 + 2 <= 15) inner[r] += u.z * xm[r][i0 + 2];
                    if (i0 + 3 <= 15) inner[r] += u.w * xm[r][i0 + 3];
                }
            }
            #pragma unroll
            for (int r = 0; r < 4; ++r) t2[r] += xm[r][v] * inner[r];
        }

        // out[b,c,w] = sum_xx (t2 + v1[xx]) * x[xx]  -- DPP row-16 reduction
        float cv[4];
        #pragma unroll
        for (int r = 0; r < 4; ++r) cv[r] = (t2[r] + v1x) * xo[r];
        #pragma unroll
        for (int r = 0; r < 4; ++r) cv[r] = row16_sum(cv[r]);
        if (xx == 0) {
            #pragma unroll
            for (int r = 0; r < 4; ++r)
                if (slot + r < cnt)
                    out[(size_t)bidx[r] * (C_ * EQ) + c * EQ + w] = cv[r];
        }
    }
}

// ---------------------------------------------------------------------------
extern "C" void kernel_launch(void* const* d_in, const int* in_sizes, int n_in,
                              void* d_out, int out_size, void* d_ws, size_t ws_size,
                              hipStream_t stream) {
    const float* x    = (const float*)d_in[0];
    const float* y    = (const float*)d_in[1];
    const float* U3   = (const float*)d_in[2];
    const float* U2   = (const float*)d_in[3];
    const float* U1   = (const float*)d_in[4];
    const float* wmax = (const float*)d_in[5];
    const float* w2   = (const float*)d_in[6];
    const float* w1   = (const float*)d_in[7];
    float* out = (float*)d_out;
    char*  ws  = (char*)d_ws;

    int*   cnt_g  = (int*)(ws + WS_CNT);
    int*   list_g = (int*)(ws + WS_LIST);
    float* Sg     = (float*)(ws + WS_S);
    float* SKLg   = (float*)(ws + WS_SKL);
    (void)ws_size;   // 51.3 MB needed; harness ws confirmed >= 66 MB

    k_skl<<<dim3(48), 192, 0, stream>>>(U3, U2, SKLg);
    k_s<<<dim3(49, E_, 4), 256, 0, stream>>>(SKLg, wmax, w2, y, Sg, cnt_g, list_g);
    k_main<<<dim3(C_ * EQ, E_), 256, 0, stream>>>(x, Sg, U1, w1, cnt_g, list_g, out);
}

// Round 14
// 122.555 us; speedup vs baseline: 1.0368x; 1.0368x over previous
//
#include <hip/hip_runtime.h>

// Problem constants
#define B_    1024
#define C_    128
#define ELL   16
#define EQ    3
#define E_    10
#define P3    23
#define P2    5
#define NSEG  176            // padded segment row: 16 f4-aligned v-segments
#define RSTR  180            // row stride (180%32=20 -> 8 bank-starts x2 = 2-way, free)
#define SRS   (48 * RSTR)    // 8640 floats per (e,c) S-slice
#define KD    28             // folded weight depth: 23 (wmax) + 5 (w2)

// packed fp32 pair: clang emits v_pk_fma_f32 / v_pk_mul_f32 for <2 x float>
typedef float v2f __attribute__((ext_vector_type(2)));

// ws layout (bytes)
#define WS_CNT   0
#define WS_LIST  64
#define WS_S     65536       // Sg: 10*128*8640*4 = 44.24 MB (ws >= 66 MB)

// segment offsets: v-th segment holds [lin_v, Q_vv, Q_v,v+1, .., Q_v,15, pad0s]
// lengths (real) 17-v, padded to x4: {20,16,16,16,16,12,12,12,12,8,8,8,8,4,4,4}
#define SEG_OFF_INIT {0,20,36,52,68,84,96,108,120,132,140,148,156,164,168,172}

// DPP row_ror add: lane i += lane (i+N) mod 16 within its 16-lane DPP row.
// Chained over N=1,2,4,8: width-16 sum-to-all; bit-identical tree to the
// __shfl_xor butterfly for the storing lanes. VERIFIED r18b/r19/r20/r23/r24.
template <int CTRL>
__device__ __forceinline__ float dpp_ror_add(float v) {
    int s = __float_as_int(v);
    int r = __builtin_amdgcn_update_dpp(s, s, CTRL, 0xF, 0xF, false);
    return v + __int_as_float(r);
}
__device__ __forceinline__ float row16_sum(float v) {
    v = dpp_ror_add<0x121>(v);   // row_ror:1
    v = dpp_ror_add<0x122>(v);   // row_ror:2
    v = dpp_ror_add<0x124>(v);   // row_ror:4
    v = dpp_ror_add<0x128>(v);   // row_ror:8
    return v;
}

// ---------------------------------------------------------------------------
// Bucketing: bucket batch indices by element, pad each bucket to x64 by
// replicating the last real index (k_main needs no load guards). Exact r19.
__device__ void do_lists(const float* __restrict__ y, int* __restrict__ cnt_g,
                         int* __restrict__ list_g, int t) {
    __shared__ int lcnt[E_];
    if (t < E_) lcnt[t] = 0;
    __syncthreads();
    for (int r = 0; r < 4; ++r) {
        int b = t + 256 * r;
        int e = 0;
        #pragma unroll
        for (int j = 1; j < E_; ++j)
            if (y[b * E_ + j] > 0.5f) e = j;
        int slot = atomicAdd(&lcnt[e], 1);
        list_g[e * B_ + slot] = b;
    }
    __syncthreads();
    if (t < E_) {
        int c0 = lcnt[t];
        cnt_g[t] = c0;
        int last = (c0 > 0) ? list_g[t * B_ + c0 - 1] : 0;
        int cp = (c0 + 63) & ~63;
        if (cp > B_) cp = B_;
        for (int s2 = c0; s2 < cp; ++s2) list_g[t * B_ + s2] = last;
    }
}

// ---------------------------------------------------------------------------
// k_s r25 = EXACT r17 (verified win; r24's SKL-hoist regressed 2-4us and is
// reverted -- the scattered phase-1b loads were L2-hits off critical path).
__global__ __launch_bounds__(256, 2) void k_s(const float* __restrict__ U3,
                                              const float* __restrict__ U2,
                                              const float* __restrict__ wmax,
                                              const float* __restrict__ w2,
                                              const float* __restrict__ y,
                                              float* __restrict__ Sg,
                                              int* __restrict__ cnt_g,
                                              int* __restrict__ list_g) {
    const int t = threadIdx.x;
    if (blockIdx.x == 48) {
        if (blockIdx.y == 0 && blockIdx.z == 0) do_lists(y, cnt_g, list_g, t);
        return;
    }
    __shared__ __align__(16) float wsm[KD * 32];          //  3,584 B
    __shared__ __align__(16) float SKL[NSEG * KD];        // 19,712 B

    const int j  = blockIdx.x;
    const int e  = blockIdx.y;
    const int cq = blockIdx.z;

    // ---- phase 1a: folded weight table (23 wmax + 5 w2) for this (e, cq)
    for (int idx = t; idx < KD * 32; idx += 256) {
        int k = idx >> 5, cc = idx & 31, c = cq * 32 + cc;
        wsm[idx] = (k < 23) ? wmax[(e * P3 + k) * C_ + c]
                            : w2[(e * P2 + (k - 23)) * C_ + c];
    }

    // ---- phase 1b: symmetrized coefficient rows, straight from global U3/U2
    if (t < NSEG) {
        const int SO[16] = SEG_OFF_INIT;
        int v = 0;
        #pragma unroll
        for (int s = 1; s < 16; ++s) v += (t >= SO[s]) ? 1 : 0;
        const int l    = t - SO[v];
        const int real = 17 - v;

        float row[KD];
        #pragma unroll
        for (int d = 0; d < KD; ++d) row[d] = 0.f;

        if (l == 0) {
            #pragma unroll
            for (int q = 0; q < P2; ++q)
                row[23 + q] = U2[(size_t)j * (ELL * P2) + v * P2 + q];
        } else if (l < real) {
            int i = v + l - 1;
            const float* pa = U3 + (size_t)j * (ELL * ELL * P3) + (v * ELL + i) * P3;
            const float* pb = U3 + (size_t)j * (ELL * ELL * P3) + (i * ELL + v) * P3;
            if (i != v) {
                #pragma unroll
                for (int k = 0; k < P3; ++k) row[k] = pa[k] + pb[k];
            } else {
                #pragma unroll
                for (int k = 0; k < P3; ++k) row[k] = pa[k];
            }
        }   // else: pad slot -> stays zero

        float* dst = &SKL[t * KD];
        #pragma unroll
        for (int d4 = 0; d4 < KD / 4; ++d4)
            *(float4*)(dst + 4 * d4) = make_float4(row[4 * d4], row[4 * d4 + 1],
                                                   row[4 * d4 + 2], row[4 * d4 + 3]);
    }
    __syncthreads();

    if (t >= NSEG) return;

    // ---- phase 2: 4 slots x 8 c per thread, packed fp32
    const int sg = t % 44;          // slot group: slots sg, sg+44, sg+88, sg+132
    const int cg = t / 44;          // 0..3 -> c8 = cg*8
    const int c8 = cg * 8;

    v2f acc[4][4];                  // [s][c-pair]
    #pragma unroll
    for (int s = 0; s < 4; ++s)
        #pragma unroll
        for (int cp2 = 0; cp2 < 4; ++cp2) acc[s][cp2] = (v2f){0.f, 0.f};

    #pragma unroll
    for (int k4 = 0; k4 < KD / 4; ++k4) {
        float4 sk4[4];
        #pragma unroll
        for (int s = 0; s < 4; ++s)
            sk4[s] = *(const float4*)&SKL[(sg + 44 * s) * KD + 4 * k4];
        #pragma unroll
        for (int kk = 0; kk < 4; ++kk) {
            const int k = 4 * k4 + kk;
            float4 w0 = *(const float4*)&wsm[k * 32 + c8];
            float4 w1 = *(const float4*)&wsm[k * 32 + c8 + 4];
            v2f wp0 = {w0.x, w0.y}, wp1 = {w0.z, w0.w};
            v2f wp2 = {w1.x, w1.y}, wp3 = {w1.z, w1.w};
            #pragma unroll
            for (int s = 0; s < 4; ++s) {
                const float skv = (kk == 0) ? sk4[s].x : (kk == 1) ? sk4[s].y
                                : (kk == 2) ? sk4[s].z : sk4[s].w;
                acc[s][0] += skv * wp0;
                acc[s][1] += skv * wp1;
                acc[s][2] += skv * wp2;
                acc[s][3] += skv * wp3;
            }
        }
    }

    // ---- stores: lane-consecutive in slot -> coalesced 44-lane runs
    #pragma unroll
    for (int s = 0; s < 4; ++s) {
        const int slot = sg + 44 * s;
        #pragma unroll
        for (int cc = 0; cc < 8; ++cc) {
            const int c = cq * 32 + c8 + cc;
            Sg[(size_t)(e * C_ + c) * SRS + j * RSTR + slot] = acc[s][cc >> 1][cc & 1];
        }
    }
}

// ---------------------------------------------------------------------------
// k_main r25: W-MERGE. One block per (e,c) handles all 3 w's (grid 128x10).
// r24 cycle accounting: 15 waves/SIMD x ~3240 issue-cyc = ~35us at the
// ~1.4GHz sustained VALU clock; measured 42 -> ~20% stall share. The
// three old (c,w) blocks duplicated the x-row gather (21 VMEM issues each
// for the SAME 4 rows) and each paid their own stage+barrier. Merged:
//   stage 48 rows once (34.6KB LDS, 4 blocks/CU still fits (256,4)),
//   load bidx/xm/xo ONCE, then unroll(disable) w-loop reuses them 3x.
// Per unit work: VMEM issues /3, barriers /3; FMA + LDS reads unchanged;
// per-thread live set unchanged (t2/inner reused across w iterations;
// runtime-w v3p is a dynamic LDS address -- legal; v1x recomputed per
// iteration to avoid dynamic register indexing, rule #20).
// Tripwire: VGPR>100 or WRITE>>12.3MB = w-loop hoisted LDS reads -> revert.
// CRITICAL (unchanged): per-chunk __syncthreads() + unroll(disable) on the
// chunk loop -- LICM hoisting LDS reads caused the r5/r6 spill blowup.
__global__ __launch_bounds__(256, 4) void k_main(
    const float* __restrict__ x, const float* __restrict__ Sg,
    const float* __restrict__ U1, const float* __restrict__ w1,
    const int* __restrict__ cnt_g, const int* __restrict__ list_g,
    float* __restrict__ out) {

    __shared__ __align__(16) float V3L[48 * RSTR];   // 34,560 B

    const int t  = threadIdx.x;
    const int c  = blockIdx.x;
    const int e  = blockIdx.y;
    const int xx = t & 15, bs = t >> 4;
    const int cnt  = cnt_g[e];
    const int cntp = (cnt + 63) & ~63;

    // ---- fill V3L: all 48 rows = 8640 floats = 2160 f4, straight copy
    {
        const float4* src = (const float4*)(Sg + (size_t)(e * C_ + c) * SRS);
        float4* dst = (float4*)V3L;
        #pragma unroll
        for (int r = 0; r < 8; ++r) dst[t + 256 * r] = src[t + 256 * r];
        if (t < 112) dst[2048 + t] = src[2048 + t];
    }
    const float w1ec = w1[e * C_ + c];
    __syncthreads();

    const int SO[16] = SEG_OFF_INIT;

    // ---- chunk loop: 64 rows per chunk, 4 per thread ----
    #pragma clang loop unroll(disable)
    for (int base = 0; base < cntp; base += 64) {
        __syncthreads();   // anti-LICM liveness pin (see header note)

        const int slot = base + bs * 4;
        int bidx[4];
        #pragma unroll
        for (int r = 0; r < 4; ++r) bidx[r] = list_g[e * B_ + slot + r];

        float xm[4][16];
        float xo[4];
        #pragma unroll
        for (int r = 0; r < 4; ++r) {
            const float* xb = x + ((size_t)bidx[r] * C_ + c) * ELL;
            #pragma unroll
            for (int i4 = 0; i4 < 4; ++i4) {
                float4 a = ((const float4*)xb)[i4];
                xm[r][4 * i4 + 0] = a.x; xm[r][4 * i4 + 1] = a.y;
                xm[r][4 * i4 + 2] = a.z; xm[r][4 * i4 + 3] = a.w;
            }
            xo[r] = xb[xx];   // own-x element (L1 hit; no dynamic reg index)
        }

        // ---- w-loop: reuse xm/xo for all 3 w's; unroll(disable) keeps the
        // 44 f4 LDS reads of each w inside its own iteration (no 132-f4
        // hoist -> no register blowup).
        #pragma clang loop unroll(disable)
        for (int w = 0; w < 3; ++w) {
            const float* v3p = &V3L[(w * 16 + xx) * RSTR];
            const float v1x = U1[w * 16 + xx] * w1ec;

            float t2[4] = {0.f, 0.f, 0.f, 0.f};
            #pragma unroll
            for (int v = 0; v < 16; ++v) {
                const int off = SO[v];
                const int nf4 = (v == 0) ? 5 : (v < 5) ? 4 : (v < 9) ? 3
                              : (v < 13) ? 2 : 1;
                float inner[4];
                {   // first f4: [lin, Q_vv, Q_v,v+1, Q_v,v+2]
                    float4 u = *(const float4*)(v3p + off);
                    #pragma unroll
                    for (int r = 0; r < 4; ++r) {
                        float s = u.x + u.y * xm[r][v];
                        if (v + 1 <= 15) s += u.z * xm[r][v + 1];
                        if (v + 2 <= 15) s += u.w * xm[r][v + 2];
                        inner[r] = s;
                    }
                }
                #pragma unroll
                for (int q = 1; q < nf4; ++q) {
                    float4 u = *(const float4*)(v3p + off + 4 * q);
                    const int i0 = v + 4 * q - 1;
                    #pragma unroll
                    for (int r = 0; r < 4; ++r) {
                        inner[r] += u.x * xm[r][i0];
                        if (i0 + 1 <= 15) inner[r] += u.y * xm[r][i0 + 1];
                        if (i0 + 2 <= 15) inner[r] += u.z * xm[r][i0 + 2];
                        if (i0 + 3 <= 15) inner[r] += u.w * xm[r][i0 + 3];
                    }
                }
                #pragma unroll
                for (int r = 0; r < 4; ++r) t2[r] += xm[r][v] * inner[r];
            }

            // out[b,c,w] = sum_xx (t2 + v1[xx]) * x[xx] -- DPP row-16 reduce
            float cv[4];
            #pragma unroll
            for (int r = 0; r < 4; ++r) cv[r] = (t2[r] + v1x) * xo[r];
            #pragma unroll
            for (int r = 0; r < 4; ++r) cv[r] = row16_sum(cv[r]);
            if (xx == 0) {
                #pragma unroll
                for (int r = 0; r < 4; ++r)
                    if (slot + r < cnt)
                        out[(size_t)bidx[r] * (C_ * EQ) + c * EQ + w] = cv[r];
            }
        }
    }
}

// ---------------------------------------------------------------------------
extern "C" void kernel_launch(void* const* d_in, const int* in_sizes, int n_in,
                              void* d_out, int out_size, void* d_ws, size_t ws_size,
                              hipStream_t stream) {
    const float* x    = (const float*)d_in[0];
    const float* y    = (const float*)d_in[1];
    const float* U3   = (const float*)d_in[2];
    const float* U2   = (const float*)d_in[3];
    const float* U1   = (const float*)d_in[4];
    const float* wmax = (const float*)d_in[5];
    const float* w2   = (const float*)d_in[6];
    const float* w1   = (const float*)d_in[7];
    float* out = (float*)d_out;
    char*  ws  = (char*)d_ws;

    int*   cnt_g  = (int*)(ws + WS_CNT);
    int*   list_g = (int*)(ws + WS_LIST);
    float* Sg     = (float*)(ws + WS_S);
    (void)ws_size;   // 44.3 MB needed; harness ws confirmed >= 66 MB

    k_s<<<dim3(49, E_, 4), 256, 0, stream>>>(U3, U2, wmax, w2, y, Sg, cnt_g, list_g);
    k_main<<<dim3(C_, E_), 256, 0, stream>>>(x, Sg, U1, w1, cnt_g, list_g, out);
}